// Round 5
// baseline (157.381 us; speedup 1.0000x reference)
//
#include <hip/hip_runtime.h>

typedef unsigned short u16;
typedef unsigned int u32;
typedef __attribute__((ext_vector_type(8))) short short8;
typedef __attribute__((ext_vector_type(4))) short short4v;
typedef __attribute__((ext_vector_type(4))) float floatx4;

#define HH 128
#define WW 128
#define XP 72   // u16 pitch of px-major LDS tiles (144 B, b128-aligned)

__device__ __forceinline__ float bf2f(u16 u) {
    u32 b = ((u32)u) << 16;
    return __builtin_bit_cast(float, b);
}
__device__ __forceinline__ u16 f2bf(float f) {
    u32 b = __builtin_bit_cast(u32, f);
    b += 0x7FFFu + ((b >> 16) & 1u);
    return (u16)(b >> 16);
}

// ws layout (bytes):
//   [0,4)                  flag: 1 = fp32 inputs, 0 = bf16 inputs
//   [256, +73728)          w3p  bf16 A-frag (18 ks * 2048)
//   [73984, +204800)       w5p  bf16 A-frag (50 ks * 2048), pre-scaled by wr0[oc]
//   [278784, +73728)       wdw  bf16 A-frag (18 ks * 2048), diag depthwise wr[oc][1+g]
//   [352512, +512)         scal fp32: b3[64], bias5[64]=wr0*b5+br
//   [353024, +16777216)    xt  bf16 [b][h][w][ic]
//   [17130240, +16777216)  y3t bf16 [b][h][w][oc]
#define W3P_BYTE 256
#define W5P_BYTE 73984
#define WDW_BYTE 278784
#define SCAL_BYTE 352512
#define XT_BYTE 353024
#define Y3T_BYTE 17130240
#define N_W3P 36864
#define N_W5P 102400
#define N_WDW 36864
#define N_SCAL 128
#define PACK_N (N_W3P + N_W5P + N_WDW + N_SCAL)

__global__ __launch_bounds__(256) void sniff_kernel(const u16* __restrict__ xu,
                                                    int* __restrict__ flag) {
    __shared__ int cnt;
    if (threadIdx.x == 0) cnt = 0;
    __syncthreads();
    int c = 0;
    for (int k = 0; k < 8; ++k) {
        int idx = 2 * (threadIdx.x * 8 + k);
        u16 u = xu[idx];
        int e = (u >> 7) & 0xFF;
        if (e >= 140) c++;
    }
    atomicAdd(&cnt, c);
    __syncthreads();
    if (threadIdx.x == 0) *flag = (cnt >= 8) ? 1 : 0;
}

__device__ __forceinline__ float load_any(const void* p, int i, int isf32) {
    return isf32 ? ((const float*)p)[i] : bf2f(((const u16*)p)[i]);
}

// A-frag order: elem = ks*2048 + mt*512 + lane*8 + j  holds
// A[oc=mt*16+(lane&15)][k=ks*32+((lane>>4)&3)*8+j], k = tap*64+ic.
__global__ __launch_bounds__(256) void prepack(
        const void* w3, const void* b3, const void* w5, const void* b5,
        const void* wr, const void* br, const int* __restrict__ flag,
        u16* __restrict__ w3p, u16* __restrict__ w5p, u16* __restrict__ wdw,
        float* __restrict__ scal) {
    int i = blockIdx.x * 256 + threadIdx.x;
    if (i >= PACK_N) return;
    int f = *flag;
    if (i < N_W3P + N_W5P + N_WDW) {
        int which = (i < N_W3P) ? 0 : (i < N_W3P + N_W5P ? 1 : 2);
        int ii = (which == 0) ? i : (which == 1 ? i - N_W3P : i - N_W3P - N_W5P);
        int j = ii & 7, lane = (ii >> 3) & 63, mt = (ii >> 9) & 3, ks = ii >> 11;
        int oc = mt * 16 + (lane & 15);
        int k = ks * 32 + ((lane >> 4) & 3) * 8 + j;
        int tap = k >> 6, ic = k & 63;
        float v;
        if (which == 0)      v = load_any(w3, (oc * 64 + ic) * 9 + tap, f);
        else if (which == 1) v = load_any(wr, oc * 10, f) *
                                 load_any(w5, (oc * 64 + ic) * 25 + tap, f);
        else                 v = (ic == oc) ? load_any(wr, oc * 10 + 1 + tap, f) : 0.f;
        u16 o = f2bf(v);
        if (which == 0)      w3p[ii] = o;
        else if (which == 1) w5p[ii] = o;
        else                 wdw[ii] = o;
    } else {
        int i2 = i - N_W3P - N_W5P - N_WDW;
        float v;
        if (i2 < 64) v = load_any(b3, i2, f);
        else {
            int c = i2 - 64;
            v = load_any(wr, c * 10, f) * load_any(b5, c, f) + load_any(br, c, f);
        }
        scal[i2] = v;
    }
}

// x [b][ic][h][w] (fp32 or bf16)  ->  xt [b][h][w][ic] bf16.
__global__ __launch_bounds__(256) void transpose_x(
        const void* __restrict__ x, const int* __restrict__ flag,
        u16* __restrict__ xt) {
    __shared__ u16 tbuf[32 * XP];
    const int b = blockIdx.z, h = blockIdx.y, w0 = blockIdx.x * 32;
    const int t = threadIdx.x;
    const int f = *flag;
    if (f) {
        const int w2 = t & 15, ic = t >> 4;
#pragma unroll
        for (int p = 0; p < 4; ++p) {
            int icc = ic + p * 16;
            const float* src = (const float*)x +
                (((size_t)(b * 64 + icc) * 128 + h) * 128 + w0 + 2 * w2);
            float2 v = *(const float2*)src;
            tbuf[(2 * w2) * XP + icc]     = f2bf(v.x);
            tbuf[(2 * w2 + 1) * XP + icc] = f2bf(v.y);
        }
    } else {
        const int w4 = t & 7, ic = t >> 3;
#pragma unroll
        for (int p = 0; p < 2; ++p) {
            int icc = ic + p * 32;
            const u16* src = (const u16*)x +
                (((size_t)(b * 64 + icc) * 128 + h) * 128 + w0 + 4 * w4);
            short4v v = *(const short4v*)src;
#pragma unroll
            for (int e = 0; e < 4; ++e)
                tbuf[(4 * w4 + e) * XP + icc] = (u16)v[e];
        }
    }
    __syncthreads();
    const int w = t >> 3, q = t & 7;
    short8 v = *(const short8*)&tbuf[w * XP + q * 8];
    *(short8*)(xt + ((size_t)((b * 128 + h) * 128) + w0 + w) * 64 + q * 8) = v;
}

// Stage a px-major halo tile from [.][h][w][64] bf16 into LDS [npx][XP].
__device__ __forceinline__ void stage_tile(
        const u16* __restrict__ src, u16* __restrict__ dst,
        int b, int h0, int w0, int halo, int cols, int npx, int iters, int tid) {
    const int q8 = tid & 7, p0 = tid >> 3;
    for (int it = 0; it < iters; ++it) {
        int px = p0 + it * 32;
        if (px < npx) {
            int r = px / cols, c = px - r * cols;
            int gh = h0 + r - halo, gw = w0 + c - halo;
            short8 v = {0, 0, 0, 0, 0, 0, 0, 0};
            if ((unsigned)gh < (unsigned)HH && (unsigned)gw < (unsigned)WW)
                v = *(const short8*)(src +
                        ((size_t)((b * 128 + gh) * 128 + gw)) * 64 + q8 * 8);
            *(short8*)&dst[px * XP + q8 * 8] = v;
        }
    }
}

#define LOAD_A4(dst, wp, ks)                                                   \
    {                                                                          \
        const u16* _ap = (wp) + (size_t)(ks) * 2048 + lane * 8;                \
        dst[0] = *(const short8*)(_ap);                                        \
        dst[1] = *(const short8*)(_ap + 512);                                  \
        dst[2] = *(const short8*)(_ap + 1024);                                 \
        dst[3] = *(const short8*)(_ap + 1536);                                 \
    }

// 2 n-tiles (rows wv2+0, wv2+1), 4 m-tiles, one k-step (32 k) at tap (kh,kw).
#define TAP2(afr, kh, kw, s, COLS)                                             \
    {                                                                          \
        const u16* _bp = &xs[((wv2 + (kh)) * (COLS) + cb + (kw)) * XP +        \
                             (s) * 32 + q * 8];                                \
        short8 _b0 = *(const short8*)_bp;                                      \
        short8 _b1 = *(const short8*)(_bp + (COLS) * XP);                      \
        acc[0][0] = __builtin_amdgcn_mfma_f32_16x16x32_bf16(afr[0], _b0, acc[0][0], 0, 0, 0); \
        acc[1][0] = __builtin_amdgcn_mfma_f32_16x16x32_bf16(afr[1], _b0, acc[1][0], 0, 0, 0); \
        acc[2][0] = __builtin_amdgcn_mfma_f32_16x16x32_bf16(afr[2], _b0, acc[2][0], 0, 0, 0); \
        acc[3][0] = __builtin_amdgcn_mfma_f32_16x16x32_bf16(afr[3], _b0, acc[3][0], 0, 0, 0); \
        acc[0][1] = __builtin_amdgcn_mfma_f32_16x16x32_bf16(afr[0], _b1, acc[0][1], 0, 0, 0); \
        acc[1][1] = __builtin_amdgcn_mfma_f32_16x16x32_bf16(afr[1], _b1, acc[1][1], 0, 0, 0); \
        acc[2][1] = __builtin_amdgcn_mfma_f32_16x16x32_bf16(afr[2], _b1, acc[2][1], 0, 0, 0); \
        acc[3][1] = __builtin_amdgcn_mfma_f32_16x16x32_bf16(afr[3], _b1, acc[3][1], 0, 0, 0); \
    }

// conv3: y3 = conv3x3(x)+b3 -> y3t [b][h][w][oc] bf16.  Tile 8 rows x 16 cols.
__global__ __launch_bounds__(256, 4) void conv3_mfma(
        const u16* __restrict__ xt, const u16* __restrict__ w3p,
        const float* __restrict__ scal, u16* __restrict__ y3t) {
    __shared__ u16 xs[180 * XP];   // 25920 B (10 x 18 halo tile)
    const int b = blockIdx.z, h0 = blockIdx.y * 8, w0 = blockIdx.x * 16;
    const int tid = threadIdx.x;
    stage_tile(xt, xs, b, h0, w0, 1, 18, 180, 6, tid);
    __syncthreads();

    const int wv = tid >> 6, lane = tid & 63, cb = lane & 15, q = lane >> 4;
    const int wv2 = wv * 2;
    floatx4 acc[4][2];
#pragma unroll
    for (int mt = 0; mt < 4; ++mt) {
        acc[mt][0] = (floatx4){0.f, 0.f, 0.f, 0.f};
        acc[mt][1] = (floatx4){0.f, 0.f, 0.f, 0.f};
    }

    short8 aA[4], aB[4];
    LOAD_A4(aA, w3p, 0);
#pragma unroll 1
    for (int kk = 0; kk < 18; kk += 2) {
        const int tap = kk >> 1;
        const int kh = tap / 3, kw = tap - kh * 3;
        LOAD_A4(aB, w3p, kk + 1);
        TAP2(aA, kh, kw, 0, 18);
        if (kk + 2 < 18) LOAD_A4(aA, w3p, kk + 2);
        TAP2(aB, kh, kw, 1, 18);
    }

    // D -> LDS [128 px][XP] (alias xs), then coalesced b128 global stores.
    __syncthreads();
    u16* yb = xs;   // 128*72*2 = 18432 <= 25920
    const float* b3f = scal;
#pragma unroll
    for (int mt = 0; mt < 4; ++mt)
#pragma unroll
        for (int nt = 0; nt < 2; ++nt) {
            int px = (wv2 + nt) * 16 + cb;
#pragma unroll
            for (int p2 = 0; p2 < 2; ++p2) {
                int oc0 = mt * 16 + q * 4 + 2 * p2;
                u32 lo = f2bf(acc[mt][nt][2 * p2]     + b3f[oc0]);
                u32 hi = f2bf(acc[mt][nt][2 * p2 + 1] + b3f[oc0 + 1]);
                *(u32*)&yb[px * XP + oc0] = lo | (hi << 16);
            }
        }
    __syncthreads();
#pragma unroll
    for (int it = 0; it < 4; ++it) {
        int u = tid + 256 * it;
        int px = u >> 3, q8 = u & 7;
        short8 v = *(const short8*)&yb[px * XP + q8 * 8];
        int gh = h0 + (px >> 4), gw = w0 + (px & 15);
        *(short8*)(y3t + ((size_t)((b * 128 + gh) * 128 + gw)) * 64 + q8 * 8) = v;
    }
}

// conv5 + fused depthwise remap:
// acc = wr0*conv5(x)  (w5p pre-scaled)  +  sum_g wr_g * shift_g(y3)  (diag MFMA)
// out = acc + bias5,  bias5 = wr0*b5 + br.
__global__ __launch_bounds__(256, 4) void conv5_mfma(
        const u16* __restrict__ xt, const u16* __restrict__ w5p,
        const u16* __restrict__ wdw, const float* __restrict__ scal,
        const int* __restrict__ flag, const u16* __restrict__ y3t,
        void* __restrict__ out) {
    __shared__ u16 xs[240 * XP];   // 34560 B (12 x 20 halo tile)
    const int b = blockIdx.z, h0 = blockIdx.y * 8, w0 = blockIdx.x * 16;
    const int tid = threadIdx.x;
    const int f = *flag;
    stage_tile(xt, xs, b, h0, w0, 2, 20, 240, 8, tid);
    __syncthreads();

    const int wv = tid >> 6, lane = tid & 63, cb = lane & 15, q = lane >> 4;
    const int wv2 = wv * 2;
    floatx4 acc[4][2];
#pragma unroll
    for (int mt = 0; mt < 4; ++mt) {
        acc[mt][0] = (floatx4){0.f, 0.f, 0.f, 0.f};
        acc[mt][1] = (floatx4){0.f, 0.f, 0.f, 0.f};
    }

    short8 aA[4], aB[4];
    LOAD_A4(aA, w5p, 0);
#pragma unroll 1
    for (int kk = 0; kk < 50; kk += 2) {
        const int tap = kk >> 1;
        const int kh = tap / 5, kw = tap - kh * 5;
        LOAD_A4(aB, w5p, kk + 1);
        TAP2(aA, kh, kw, 0, 20);
        if (kk + 2 < 50) LOAD_A4(aA, w5p, kk + 2);
        TAP2(aB, kh, kw, 1, 20);
    }

    // Stage y3 halo tile (10 x 18) into xs (x no longer needed), then 9
    // depthwise "taps" as diagonal MFMA: kh=2-sw, kw=2-sh for g=sh*3+sw.
    __syncthreads();
    stage_tile(y3t, xs, b, h0, w0, 1, 18, 180, 6, tid);
    __syncthreads();

    LOAD_A4(aA, wdw, 0);
#pragma unroll 1
    for (int kk = 0; kk < 18; kk += 2) {
        const int g = kk >> 1;
        const int sh = g / 3, sw = g - sh * 3;
        const int kh = 2 - sw, kw = 2 - sh;
        LOAD_A4(aB, wdw, kk + 1);
        TAP2(aA, kh, kw, 0, 18);
        if (kk + 2 < 18) LOAD_A4(aA, wdw, kk + 2);
        TAP2(aB, kh, kw, 1, 18);
    }

    const float* bias5 = scal + 64;
#pragma unroll
    for (int mt = 0; mt < 4; ++mt)
#pragma unroll
        for (int nt = 0; nt < 2; ++nt) {
            int gh = h0 + wv2 + nt;
#pragma unroll
            for (int reg = 0; reg < 4; ++reg) {
                int oc = mt * 16 + q * 4 + reg;
                float s = acc[mt][nt][reg] + bias5[oc];
                size_t oidx = ((size_t)(b * 64 + oc) * HH + gh) * WW + w0 + cb;
                if (f) ((float*)out)[oidx] = s;
                else   ((u16*)out)[oidx]   = f2bf(s);
            }
        }
}

extern "C" void kernel_launch(void* const* d_in, const int* in_sizes, int n_in,
                              void* d_out, int out_size, void* d_ws, size_t ws_size,
                              hipStream_t stream) {
    const void* x  = d_in[0];
    const void* w3 = d_in[1];
    const void* b3 = d_in[2];
    const void* w5 = d_in[3];
    const void* b5 = d_in[4];
    const void* wr = d_in[5];
    const void* br = d_in[6];

    int*   flag = (int*)d_ws;
    u16*   w3p  = (u16*)((char*)d_ws + W3P_BYTE);
    u16*   w5p  = (u16*)((char*)d_ws + W5P_BYTE);
    u16*   wdw  = (u16*)((char*)d_ws + WDW_BYTE);
    float* scal = (float*)((char*)d_ws + SCAL_BYTE);
    u16*   xt   = (u16*)((char*)d_ws + XT_BYTE);
    u16*   y3t  = (u16*)((char*)d_ws + Y3T_BYTE);

    sniff_kernel<<<1, 256, 0, stream>>>((const u16*)x, flag);
    prepack<<<(PACK_N + 255) / 256, 256, 0, stream>>>(w3, b3, w5, b5, wr, br, flag,
                                                      w3p, w5p, wdw, scal);
    transpose_x<<<dim3(4, 128, 8), 256, 0, stream>>>(x, flag, xt);

    dim3 grid(WW / 16, HH / 8, 8);
    conv3_mfma<<<grid, 256, 0, stream>>>(xt, w3p, scal, y3t);
    conv5_mfma<<<grid, 256, 0, stream>>>(xt, w5p, wdw, scal, flag, y3t, d_out);
}